// Round 5
// baseline (228.887 us; speedup 1.0000x reference)
//
#include <hip/hip_runtime.h>
#include <math.h>

#define NROWS 8192
#define DIMX  1024
#define DKV   128
#define KSPLIT 8
#define KEYS_PER_SPLIT (NROWS / KSPLIT)  // 1024
#define BN 64
#define NW (DKV * DIMX)                  // 131072

typedef __attribute__((ext_vector_type(8))) short bf16x8;
typedef __attribute__((ext_vector_type(4))) float f32x4;

static __device__ __forceinline__ short f2bf(float f) {
    union { float f; unsigned u; } v; v.f = f;
    unsigned r = v.u + 0x7fff + ((v.u >> 16) & 1);  // RNE
    return (short)(r >> 16);
}
static __device__ __forceinline__ float bf2f(short s) {
    union { unsigned u; float f; } v; v.u = ((unsigned)(unsigned short)s) << 16;
    return v.f;
}
static __device__ __forceinline__ unsigned pack2(short lo, short hi) {
    return ((unsigned)(unsigned short)hi << 16) | (unsigned short)lo;
}

// ---------------------------------------------------------------------------
// wconv: Wqk, Wv fp32 -> bf16 (1 MB traffic)
// ---------------------------------------------------------------------------
__global__ __launch_bounds__(256) void wconv_kernel(
    const float* __restrict__ Wqk, const float* __restrict__ Wv,
    short* __restrict__ wqb, short* __restrict__ wvb)
{
    const int t = blockIdx.x * 256 + threadIdx.x;   // 0..32767
    const float* src = (t < 16384) ? Wqk : Wv;
    short* dst = (t < 16384) ? wqb : wvb;
    const int off = (t & 16383) * 8;
    const float4 f0 = *(const float4*)(src + off);
    const float4 f1 = *(const float4*)(src + off + 4);
    uint4 p;
    p.x = pack2(f2bf(f0.x), f2bf(f0.y));
    p.y = pack2(f2bf(f0.z), f2bf(f0.w));
    p.z = pack2(f2bf(f1.x), f2bf(f1.y));
    p.w = pack2(f2bf(f1.z), f2bf(f1.w));
    *(uint4*)(dst + off) = p;
}

// ---------------------------------------------------------------------------
// proj: 32 rows x 128 cols per block, BK=64, grid (256, 2), 256 threads.
// A staged from fp32 x with in-register bf16 convert; B from bf16 weights.
// half 0 -> qkb row-major; half 1 -> vtb transposed. Coalesced epilogues.
// ---------------------------------------------------------------------------
__global__ __launch_bounds__(256) void proj_kernel(
    const float* __restrict__ x,
    const short* __restrict__ wqb, const float* __restrict__ bqk,
    const short* __restrict__ wvb, const float* __restrict__ bv,
    short* __restrict__ qkb, short* __restrict__ vtb)
{
    __shared__ __align__(16) short as[32 * 72];    // 32 rows x 64 k (+8 pad)
    __shared__ __align__(16) short bs[128 * 72];   // 128 cols x 64 k (+8 pad)

    const int tid = threadIdx.x;
    const int lane = tid & 63, wave = tid >> 6;
    const int l15 = lane & 15, quad = lane >> 4;
    const int rg = wave & 1, cg = wave >> 1;       // row-group, col-group
    const int r0 = blockIdx.x * 32;
    const int half = blockIdx.y;
    const short* W = half ? wvb : wqb;
    const float* bias = half ? bv : bqk;

    f32x4 acc[4];
    #pragma unroll
    for (int i = 0; i < 4; ++i) acc[i] = (f32x4)0.0f;

    const int arow = tid >> 3, ach = tid & 7;      // 32 rows x 8 chunks
    uint4 areg, breg[4];
    auto load_tiles = [&](int kc) {
        const float4 f0 = *(const float4*)(x + (size_t)(r0 + arow) * DIMX + kc + ach * 8);
        const float4 f1 = *(const float4*)(x + (size_t)(r0 + arow) * DIMX + kc + ach * 8 + 4);
        areg.x = pack2(f2bf(f0.x), f2bf(f0.y));
        areg.y = pack2(f2bf(f0.z), f2bf(f0.w));
        areg.z = pack2(f2bf(f1.x), f2bf(f1.y));
        areg.w = pack2(f2bf(f1.z), f2bf(f1.w));
        #pragma unroll
        for (int i = 0; i < 4; ++i)
            breg[i] = *(const uint4*)(W + (size_t)(arow + i * 32) * DIMX + kc + ach * 8);
    };
    auto store_tiles = [&]() {
        *(uint4*)&as[arow * 72 + ach * 8] = areg;
        #pragma unroll
        for (int i = 0; i < 4; ++i)
            *(uint4*)&bs[(arow + i * 32) * 72 + ach * 8] = breg[i];
    };

    load_tiles(0);
    store_tiles();
    __syncthreads();

    for (int kc = 0; kc < DIMX; kc += 64) {
        const bool more = (kc + 64) < DIMX;
        if (more) load_tiles(kc + 64);
        #pragma unroll
        for (int ks = 0; ks < 2; ++ks) {
            const bf16x8 a = *(const bf16x8*)&as[(rg * 16 + l15) * 72 + ks * 32 + quad * 8];
            #pragma unroll
            for (int nt = 0; nt < 4; ++nt) {
                const bf16x8 b = *(const bf16x8*)&bs[(cg * 64 + nt * 16 + l15) * 72 + ks * 32 + quad * 8];
                acc[nt] = __builtin_amdgcn_mfma_f32_16x16x32_bf16(a, b, acc[nt], 0, 0, 0);
            }
        }
        __syncthreads();
        if (more) { store_tiles(); __syncthreads(); }
    }

    // epilogue via LDS transpose (reuse bs), coalesced 16B stores
    short* ot = bs;
    if (half == 0) {
        // [32 rows][136]
        #pragma unroll
        for (int nt = 0; nt < 4; ++nt) {
            const float b = bias[cg * 64 + nt * 16 + l15];
            #pragma unroll
            for (int r = 0; r < 4; ++r)
                ot[(rg * 16 + quad * 4 + r) * 136 + cg * 64 + nt * 16 + l15] = f2bf(acc[nt][r] + b);
        }
        __syncthreads();
        #pragma unroll
        for (int i = 0; i < 2; ++i) {
            const int flat = i * 256 + tid;
            const int row = flat >> 4, sl = flat & 15;
            *(uint4*)(qkb + (size_t)(r0 + row) * DKV + sl * 8) = *(const uint4*)&ot[row * 136 + sl * 8];
        }
    } else {
        // [128 cols][48] transposed
        #pragma unroll
        for (int nt = 0; nt < 4; ++nt) {
            const float b = bias[cg * 64 + nt * 16 + l15];
            #pragma unroll
            for (int r = 0; r < 4; ++r)
                ot[(cg * 64 + nt * 16 + l15) * 48 + rg * 16 + quad * 4 + r] = f2bf(acc[nt][r] + b);
        }
        __syncthreads();
        #pragma unroll
        for (int i = 0; i < 2; ++i) {
            const int flat = i * 256 + tid;
            const int col = flat >> 2, sl = flat & 3;
            *(uint4*)(vtb + (size_t)col * NROWS + r0 + sl * 8) = *(const uint4*)&ot[col * 48 + sl * 8];
        }
    }
}

// ---------------------------------------------------------------------------
// flash (fixed-M softmax): M_i = |qk_i|^2 (diagonal score) is a valid, k-split
// independent shift: s_ij - M_i <= |qk_i|(|qk_j|-|qk_i|) ~ <= 25 -> exp safe,
// l <= ~1e12 fits fp32.  No row-max shuffles, no rescale, no m-state.
// 128 Q rows x 1024 keys per block; 4 waves x 32 rows (2 row-groups so each
// kt/vt fragment feeds 2 MFMAs).  grid (64, KSPLIT), 256 threads, 53KB LDS.
// ---------------------------------------------------------------------------
__global__ __launch_bounds__(256, 2) void flash_kernel(
    const short* __restrict__ qkb, const short* __restrict__ vtb,
    float* __restrict__ opart, float* __restrict__ lpart)
{
    __shared__ __align__(16) short kt[64 * 136];      // 64 keys x 128 d (+8)
    __shared__ __align__(16) short vt[128 * 72];      // 128 d x 64 keys (+8)
    __shared__ __align__(16) short pb[4 * 32 * 72];   // per-wave P: 32 x 64 (+8)

    const int tid  = threadIdx.x;
    const int lane = tid & 63;
    const int wave = tid >> 6;
    const int l15  = lane & 15;
    const int quad = lane >> 4;
    const int rbase = blockIdx.x * 128 + wave * 32;
    const int ks = blockIdx.y;

    // Q fragments for 2 row-groups (A layout: m=l15, k=quad*8+j per 32-block)
    bf16x8 qf[2][4];
    #pragma unroll
    for (int g = 0; g < 2; ++g) {
        const short* qrow = qkb + (size_t)(rbase + g * 16 + l15) * DKV;
        #pragma unroll
        for (int k = 0; k < 4; ++k)
            qf[g][k] = *(const bf16x8*)(qrow + k * 32 + quad * 8);
    }

    // fixed M per C-row (row = quad*4+r)
    float Mrow[2][4];
    #pragma unroll
    for (int g = 0; g < 2; ++g) {
        float ss = 0.f;
        #pragma unroll
        for (int k = 0; k < 4; ++k)
            #pragma unroll
            for (int j = 0; j < 8; ++j) {
                const float q = bf2f(qf[g][k][j]);
                ss += q * q;
            }
        ss += __shfl_xor(ss, 16);
        ss += __shfl_xor(ss, 32);          // lanes with same l15 now hold |qk_{l15}|^2
        #pragma unroll
        for (int r = 0; r < 4; ++r)
            Mrow[g][r] = __shfl(ss, quad * 4 + r, 16);  // M of C-row quad*4+r
    }

    bf16x8 ones;
    #pragma unroll
    for (int i = 0; i < 8; ++i) ones[i] = (short)0x3F80;   // bf16 1.0

    f32x4 oacc[2][8];
    #pragma unroll
    for (int g = 0; g < 2; ++g)
        #pragma unroll
        for (int i = 0; i < 8; ++i) oacc[g][i] = (f32x4)0.0f;
    f32x4 lacc[2];
    lacc[0] = (f32x4)0.0f; lacc[1] = (f32x4)0.0f;

    const int jb = ks * KEYS_PER_SPLIT, je = jb + KEYS_PER_SPLIT;

    // staging: kt = 64 rows x 16 chunks = 1024 uint4s; vt = 128 rows x 8 = 1024
    uint4 kreg[4], vreg[4];
    auto load_tile = [&](int j0) {
        #pragma unroll
        for (int i = 0; i < 4; ++i) {
            const int idx = i * 256 + tid;
            kreg[i] = *(const uint4*)(qkb + (size_t)(j0 + (idx >> 4)) * DKV + (idx & 15) * 8);
        }
        #pragma unroll
        for (int i = 0; i < 4; ++i) {
            const int idx = i * 256 + tid;
            vreg[i] = *(const uint4*)(vtb + (size_t)(idx >> 3) * NROWS + j0 + (idx & 7) * 8);
        }
    };
    auto store_tile = [&]() {
        #pragma unroll
        for (int i = 0; i < 4; ++i) {
            const int idx = i * 256 + tid;
            *(uint4*)&kt[(idx >> 4) * 136 + (idx & 15) * 8] = kreg[i];
        }
        #pragma unroll
        for (int i = 0; i < 4; ++i) {
            const int idx = i * 256 + tid;
            *(uint4*)&vt[(idx >> 3) * 72 + (idx & 7) * 8] = vreg[i];
        }
    };

    load_tile(jb);
    store_tile();
    __syncthreads();

    short* pw = &pb[wave * 32 * 72];

    for (int j0 = jb; j0 < je; j0 += BN) {
        const bool more = (j0 + BN) < je;
        if (more) load_tile(j0 + BN);      // in flight during compute

        // S = Q K^T : each kt fragment feeds both row-groups
        f32x4 s[2][4];
        #pragma unroll
        for (int nt = 0; nt < 4; ++nt) {
            f32x4 a0 = (f32x4)0.0f, a1 = (f32x4)0.0f;
            #pragma unroll
            for (int k = 0; k < 4; ++k) {
                const bf16x8 b = *(const bf16x8*)&kt[(nt * 16 + l15) * 136 + k * 32 + quad * 8];
                a0 = __builtin_amdgcn_mfma_f32_16x16x32_bf16(qf[0][k], b, a0, 0, 0, 0);
                a1 = __builtin_amdgcn_mfma_f32_16x16x32_bf16(qf[1][k], b, a1, 0, 0, 0);
            }
            s[0][nt] = a0; s[1][nt] = a1;
        }

        // P = exp(S - M) -> LDS (wave-private, no block barrier)
        #pragma unroll
        for (int g = 0; g < 2; ++g)
            #pragma unroll
            for (int nt = 0; nt < 4; ++nt)
                #pragma unroll
                for (int r = 0; r < 4; ++r)
                    pw[(g * 16 + quad * 4 + r) * 72 + nt * 16 + l15] =
                        f2bf(__expf(s[g][nt][r] - Mrow[g][r]));

        // O += P V ; l += P . 1 : each vt fragment feeds both row-groups
        #pragma unroll
        for (int k = 0; k < 2; ++k) {
            bf16x8 a[2];
            #pragma unroll
            for (int g = 0; g < 2; ++g) {
                a[g] = *(const bf16x8*)&pw[(g * 16 + l15) * 72 + k * 32 + quad * 8];
                lacc[g] = __builtin_amdgcn_mfma_f32_16x16x32_bf16(a[g], ones, lacc[g], 0, 0, 0);
            }
            #pragma unroll
            for (int nt = 0; nt < 8; ++nt) {
                const bf16x8 b = *(const bf16x8*)&vt[(nt * 16 + l15) * 72 + k * 32 + quad * 8];
                oacc[0][nt] = __builtin_amdgcn_mfma_f32_16x16x32_bf16(a[0], b, oacc[0][nt], 0, 0, 0);
                oacc[1][nt] = __builtin_amdgcn_mfma_f32_16x16x32_bf16(a[1], b, oacc[1][nt], 0, 0, 0);
            }
        }

        __syncthreads();
        if (more) { store_tile(); __syncthreads(); }
    }

    // store partials: fp32 full-line stores
    #pragma unroll
    for (int g = 0; g < 2; ++g) {
        const int rw = rbase + g * 16 + quad * 4;
        #pragma unroll
        for (int nt = 0; nt < 8; ++nt) {
            const int col = nt * 16 + l15;
            #pragma unroll
            for (int r = 0; r < 4; ++r)
                opart[((size_t)ks * NROWS + rw + r) * DKV + col] = oacc[g][nt][r];
        }
        if (l15 == 0)
            #pragma unroll
            for (int r = 0; r < 4; ++r)
                lpart[ks * NROWS + rw + r] = lacc[g][r];
    }
}

// ---------------------------------------------------------------------------
// combine: out = sum_s opart / sum_s lpart  (M is split-independent)
// ---------------------------------------------------------------------------
__global__ __launch_bounds__(256) void combine_kernel(
    const float* __restrict__ opart, const float* __restrict__ lpart,
    float* __restrict__ out)
{
    const int idx = blockIdx.x * 256 + threadIdx.x;
    const int row = idx >> 7;
    float L = 0.f, acc = 0.f;
    #pragma unroll
    for (int s = 0; s < KSPLIT; ++s) {
        L += lpart[s * NROWS + row];
        acc += opart[(size_t)s * NROWS * DKV + idx];
    }
    out[idx] = acc / L;
}

// ---------------------------------------------------------------------------
extern "C" void kernel_launch(void* const* d_in, const int* in_sizes, int n_in,
                              void* d_out, int out_size, void* d_ws, size_t ws_size,
                              hipStream_t stream) {
    const float* x   = (const float*)d_in[0];
    const float* Wqk = (const float*)d_in[1];
    const float* bqk = (const float*)d_in[2];
    const float* Wv  = (const float*)d_in[3];
    const float* bv  = (const float*)d_in[4];
    float* out = (float*)d_out;

    char* ws = (char*)d_ws;
    short* qkb   = (short*)ws;                                 // 2 MB  bf16 [N][128]
    short* vtb   = (short*)(ws + (2u << 20));                  // 2 MB  bf16 [128][N]
    short* wqb   = (short*)(ws + (4u << 20));                  // 256 KB
    short* wvb   = (short*)(ws + (4u << 20) + (256u << 10));   // 256 KB
    float* lpart = (float*)(ws + (4u << 20) + (512u << 10));   // 256 KB fp32 [KS][N]
    float* opart = (float*)(ws + (5u << 20));                  // 32 MB fp32 [KS][N][128]

    wconv_kernel<<<dim3(128), 256, 0, stream>>>(Wqk, Wv, wqb, wvb);
    proj_kernel<<<dim3(NROWS / 32, 2), 256, 0, stream>>>(x, wqb, bqk, wvb, bv, qkb, vtb);
    flash_kernel<<<dim3(NROWS / 128, KSPLIT), 256, 0, stream>>>(qkb, vtb, opart, lpart);
    combine_kernel<<<dim3(NROWS * DKV / 256), 256, 0, stream>>>(opart, lpart, out);
}